// Round 6
// baseline (136.114 us; speedup 1.0000x reference)
//
#include <hip/hip_runtime.h>

#define NUM_ENT 7
#define DIM_ENT 4
#define H 128            // NEMBED_HALF
#define OUTC (2 * H)     // 256 columns per entity
#define BPB 16           // batch elements per block (R8 geometry — best measured)

typedef float f32x4 __attribute__((ext_vector_type(4)));   // native clang vector

// R11: single-variable A/B vs R8 (129.7 us, best measured): ONLY change is
// plain stores -> __builtin_nontemporal_store on the 117 MB write-once
// output. Theory: all five prior structures (LDS-staged / register /
// 8-32 thr/elem / rolled / unrolled) cluster at dur 129.7-140.9 and the
// one measured ace dispatch streamed writes at just 1.5-1.9 TB/s while the
// harness's own fillBufferAligned does 6.4 TB/s on the same machine in the
// same loop. Invariant suspect: write-back L2 allocate+evict on 117 MB
// (29x the 4 MiB/XCD L2) of never-re-read data. nt stores stream past L2.
// If this lands in the 128-136 band instead, the alternative model (dur is
// poison-fill-dominated; ace already hidden) is confirmed -> roofline.
//
// R8 geometry: 16 threads per batch element (sub=tid&15), each owning cols
// {sub*4, sub*4+64} of both prop (0..127) and rel (128..255) halves.
// Grid = B/16 = 1024 blocks x 256 threads.
__global__ __launch_bounds__(256) void ace_kernel(
    const float* __restrict__ ctx,     // [28, B]
    const float* __restrict__ w_prop,  // [4, 128]
    const float* __restrict__ b_prop,  // [128]
    const float* __restrict__ w_rel,   // [5, 128]
    const float* __restrict__ b_rel,   // [128]
    float* __restrict__ out,           // [B, 7, 256]
    int B)
{
    __shared__ float s_ents[BPB][NUM_ENT * DIM_ENT];          // 16 x 28 floats

    const int tid = threadIdx.x;
    const int b0 = blockIdx.x * BPB;

    // Stage ents, bb-fastest for coalescing: t -> (k = t>>4, bb = t&15).
#pragma unroll
    for (int t = tid; t < BPB * NUM_ENT * DIM_ENT; t += 256) {
        const int k  = t >> 4;
        const int bb = t & 15;
        s_ents[bb][k] = ctx[(size_t)k * B + (b0 + bb)];
    }
    __syncthreads();

    const int sub = tid & 15;          // column-group within batch elem
    const int bb  = tid >> 4;          // batch elem within block (0..15)
    const int c0  = sub << 2;          // quad 0: cols c0..c0+3; quad 1: +64
    float* outb = out + (size_t)(b0 + bb) * (NUM_ENT * OUTC);

    f32x4 e[NUM_ENT];
#pragma unroll
    for (int n = 0; n < NUM_ENT; ++n)
        e[n] = *(const f32x4*)(&s_ents[bb][n * DIM_ENT]);

    {   // ---- prop_emb: relu(ents @ w_prop + b_prop) -> cols {c0, c0+64}
        f32x4 wp[DIM_ENT][2], bp[2];
#pragma unroll
        for (int f = 0; f < DIM_ENT; ++f) {
            wp[f][0] = *(const f32x4*)(w_prop + f * H + c0);
            wp[f][1] = *(const f32x4*)(w_prop + f * H + c0 + 64);
        }
        bp[0] = *(const f32x4*)(b_prop + c0);
        bp[1] = *(const f32x4*)(b_prop + c0 + 64);
#pragma unroll
        for (int n = 0; n < NUM_ENT; ++n) {
            const float e0 = e[n].x, e1 = e[n].y, e2 = e[n].z, e3 = e[n].w;
#pragma unroll
            for (int q = 0; q < 2; ++q) {
                f32x4 a = bp[q];
                a += e0 * wp[0][q];
                a += e1 * wp[1][q];
                a += e2 * wp[2][q];
                a += e3 * wp[3][q];
                a.x = fmaxf(a.x, 0.f); a.y = fmaxf(a.y, 0.f);
                a.z = fmaxf(a.z, 0.f); a.w = fmaxf(a.w, 0.f);
                __builtin_nontemporal_store(a, (f32x4*)(outb + n * OUTC + c0 + q * 64));
            }
        }
    }

    {   // ---- rel_emb: sum_{j!=i} relu(feat(i,j) @ w_rel + b_rel)
        //      -> cols {128+c0, 128+c0+64}
        f32x4 wr[DIM_ENT + 1][2], br[2];
#pragma unroll
        for (int f = 0; f < DIM_ENT + 1; ++f) {
            wr[f][0] = *(const f32x4*)(w_rel + f * H + c0);
            wr[f][1] = *(const f32x4*)(w_rel + f * H + c0 + 64);
        }
        br[0] = *(const f32x4*)(b_rel + c0);
        br[1] = *(const f32x4*)(b_rel + c0 + 64);
#pragma unroll
        for (int i = 0; i < NUM_ENT; ++i) {
            f32x4 acc0 = {0.f, 0.f, 0.f, 0.f};
            f32x4 acc1 = {0.f, 0.f, 0.f, 0.f};
#pragma unroll
            for (int j = 0; j < NUM_ENT; ++j) {
                if (j == i) continue;
                const float dx = e[i].x - e[j].x;
                const float dy = e[i].y - e[j].y;
                const float dz = e[i].z - e[j].z;
                const float dv = e[i].w - e[j].w;
                const float d  = __builtin_amdgcn_sqrtf(dx * dx + dy * dy);
                {
                    f32x4 t = br[0];
                    t += dx * wr[0][0]; t += dy * wr[1][0]; t += dz * wr[2][0];
                    t += dv * wr[3][0]; t += d  * wr[4][0];
                    acc0.x += fmaxf(t.x, 0.f); acc0.y += fmaxf(t.y, 0.f);
                    acc0.z += fmaxf(t.z, 0.f); acc0.w += fmaxf(t.w, 0.f);
                }
                {
                    f32x4 t = br[1];
                    t += dx * wr[0][1]; t += dy * wr[1][1]; t += dz * wr[2][1];
                    t += dv * wr[3][1]; t += d  * wr[4][1];
                    acc1.x += fmaxf(t.x, 0.f); acc1.y += fmaxf(t.y, 0.f);
                    acc1.z += fmaxf(t.z, 0.f); acc1.w += fmaxf(t.w, 0.f);
                }
            }
            __builtin_nontemporal_store(acc0, (f32x4*)(outb + i * OUTC + H + c0));
            __builtin_nontemporal_store(acc1, (f32x4*)(outb + i * OUTC + H + c0 + 64));
        }
    }
}

extern "C" void kernel_launch(void* const* d_in, const int* in_sizes, int n_in,
                              void* d_out, int out_size, void* d_ws, size_t ws_size,
                              hipStream_t stream) {
    const float* ctx    = (const float*)d_in[0];
    const float* w_prop = (const float*)d_in[1];
    const float* b_prop = (const float*)d_in[2];
    const float* w_rel  = (const float*)d_in[3];
    const float* b_rel  = (const float*)d_in[4];
    float* out = (float*)d_out;

    const int B = in_sizes[0] / (NUM_ENT * DIM_ENT);   // 16384
    const int nb = (B + BPB - 1) / BPB;                // 1024 blocks
    ace_kernel<<<nb, 256, 0, stream>>>(ctx, w_prop, b_prop, w_rel, b_rel, out, B);
}

// Round 7
// 130.941 us; speedup vs baseline: 1.0395x; 1.0395x over previous
//
#include <hip/hip_runtime.h>

#define NUM_ENT 7
#define DIM_ENT 4
#define H 128            // NEMBED_HALF
#define OUTC (2 * H)     // 256 columns per entity
#define BPB 8            // batch elements per block

typedef float f32x4 __attribute__((ext_vector_type(4)));   // native clang vector

// R12: store-MLP experiment. All six prior structures cluster at dur
// 129.7-136 (plain stores) with ace invariant ~57 us vs an 18 us traffic
// floor, while every pipe profiles idle (VALU 13%, HBM 19%, occ 20%).
// The fill kernel that DOES hit 6.4 TB/s issues long back-to-back store
// bursts; all our variants interleaved stores with dependent compute (few
// outstanding writes per wave). Test: compute ALL 14 output quads per
// thread into registers first, then a sched_barrier(0)-fenced burst of 14
// consecutive global_store_dwordx4 walking sequential addresses.
//
// Geometry (R7-style): 32 threads/elem. wave w, lane l: bb = w*2+(l>>5),
// c4 = (l&31)*4. Per store instruction a half-wave (one elem) writes
// 32 x 16 B stride-16 = 512 B contiguous; burst order n-prop, n-rel walks
// the elem's 7168 B region front-to-back. Plain stores (nt costs +6 us:
// R8 129.7 vs R11 136.1). VGPR ~150 (occupancy proven non-binding R9/R10).
__global__ __launch_bounds__(256) void ace_kernel(
    const float* __restrict__ ctx,     // [28, B]
    const float* __restrict__ w_prop,  // [4, 128]
    const float* __restrict__ b_prop,  // [128]
    const float* __restrict__ w_rel,   // [5, 128]
    const float* __restrict__ b_rel,   // [128]
    float* __restrict__ out,           // [B, 7, 256]
    int B)
{
    __shared__ float s_ents[BPB][NUM_ENT * DIM_ENT];          // 8 x 28 floats

    const int tid = threadIdx.x;
    const int b0 = blockIdx.x * BPB;

    // Stage ents, b-fastest for coalescing: tid -> (k = tid>>3, bb = tid&7)
    if (tid < BPB * NUM_ENT * DIM_ENT) {                      // 224 threads
        const int k  = tid >> 3;
        const int bb = tid & 7;
        s_ents[bb][k] = ctx[(size_t)k * B + (b0 + bb)];
    }
    __syncthreads();

    const int w    = tid >> 6;
    const int lane = tid & 63;
    const int bb   = w * 2 + (lane >> 5);
    const int c4   = (lane & 31) << 2;
    float* outb = out + (size_t)(b0 + bb) * (NUM_ENT * OUTC);

    const f32x4 vzero = {0.f, 0.f, 0.f, 0.f};

    // All 7 entities -> registers (aligned ds_read_b128, conflict-free:
    // 2 bb-groups/wave at 112 B stride -> disjoint bank windows, 32-lane
    // broadcast within a group is free).
    f32x4 e[NUM_ENT];
#pragma unroll
    for (int n = 0; n < NUM_ENT; ++n)
        e[n] = *(const f32x4*)(&s_ents[bb][n * DIM_ENT]);

    f32x4 pres[NUM_ENT];   // prop quads, cols c4
    f32x4 rres[NUM_ENT];   // rel quads,  cols 128+c4

    {   // ---- prop_emb: relu(ents @ w_prop + b_prop)
        const f32x4 wp0 = *(const f32x4*)(w_prop + 0 * H + c4);
        const f32x4 wp1 = *(const f32x4*)(w_prop + 1 * H + c4);
        const f32x4 wp2 = *(const f32x4*)(w_prop + 2 * H + c4);
        const f32x4 wp3 = *(const f32x4*)(w_prop + 3 * H + c4);
        const f32x4 bp  = *(const f32x4*)(b_prop + c4);
#pragma unroll
        for (int n = 0; n < NUM_ENT; ++n) {
            f32x4 a = bp;
            a += e[n].x * wp0;
            a += e[n].y * wp1;
            a += e[n].z * wp2;
            a += e[n].w * wp3;
            pres[n] = __builtin_elementwise_max(a, vzero);
        }
    }

    {   // ---- rel_emb: sum_{j!=i} relu(feat(i,j) @ w_rel + b_rel)
        const f32x4 w0 = *(const f32x4*)(w_rel + 0 * H + c4);
        const f32x4 w1 = *(const f32x4*)(w_rel + 1 * H + c4);
        const f32x4 w2 = *(const f32x4*)(w_rel + 2 * H + c4);
        const f32x4 w3 = *(const f32x4*)(w_rel + 3 * H + c4);
        const f32x4 w4 = *(const f32x4*)(w_rel + 4 * H + c4);
        const f32x4 br = *(const f32x4*)(b_rel + c4);
#pragma unroll
        for (int i = 0; i < NUM_ENT; ++i) {
            f32x4 acc = vzero;
#pragma unroll
            for (int j = 0; j < NUM_ENT; ++j) {
                if (j == i) continue;
                const float dx = e[i].x - e[j].x;
                const float dy = e[i].y - e[j].y;
                const float dz = e[i].z - e[j].z;
                const float dv = e[i].w - e[j].w;
                const float d  = __builtin_amdgcn_sqrtf(dx * dx + dy * dy);
                f32x4 t = br;
                t += dx * w0;
                t += dy * w1;
                t += dz * w2;
                t += dv * w3;
                t += d  * w4;
                acc += __builtin_elementwise_max(t, vzero);
            }
            rres[i] = acc;
        }
    }

    // Fence: keep ALL compute above, then issue the 14 stores back-to-back
    // (fill-style burst; max outstanding VMEM writes per wave).
    __builtin_amdgcn_sched_barrier(0);

#pragma unroll
    for (int n = 0; n < NUM_ENT; ++n) {
        *(f32x4*)(outb + n * OUTC + c4)     = pres[n];
        *(f32x4*)(outb + n * OUTC + H + c4) = rres[n];
    }
}

extern "C" void kernel_launch(void* const* d_in, const int* in_sizes, int n_in,
                              void* d_out, int out_size, void* d_ws, size_t ws_size,
                              hipStream_t stream) {
    const float* ctx    = (const float*)d_in[0];
    const float* w_prop = (const float*)d_in[1];
    const float* b_prop = (const float*)d_in[2];
    const float* w_rel  = (const float*)d_in[3];
    const float* b_rel  = (const float*)d_in[4];
    float* out = (float*)d_out;

    const int B = in_sizes[0] / (NUM_ENT * DIM_ENT);   // 16384
    const int nb = (B + BPB - 1) / BPB;                // 2048 blocks
    ace_kernel<<<nb, 256, 0, stream>>>(ctx, w_prop, b_prop, w_rel, b_rel, out, B);
}